// Round 1
// baseline (661.197 us; speedup 1.0000x reference)
//
#include <hip/hip_runtime.h>
#include <hip/hip_bf16.h>

#define B_ 16
#define C_ 64
#define HW_ 1024
#define N_ROWS 16384
#define NE_ 4096
#define CHW_ 65536          // C_*HW_
#define ZQ_SIZE 1048576     // B_*CHW_
#define LOSS_OFF ZQ_SIZE
#define IDX_OFF (ZQ_SIZE + 1)
#define EPS_GAP 2e-3f
#define LOSS_SCALE (1.25f / 1048576.f)

// ---- monotonic float <-> u64 key packing (score in high 32, idx in low 32)
// atomicMin over keys == argmin with lowest-index tie-break (== jnp.argmin).
__device__ __forceinline__ unsigned long long packKey(float s, int idx) {
    unsigned u = __float_as_uint(s);
    u = (u & 0x80000000u) ? ~u : (u | 0x80000000u);
    return ((unsigned long long)u << 32) | (unsigned)idx;
}
__device__ __forceinline__ float keyScore(unsigned long long k) {
    unsigned u = (unsigned)(k >> 32);
    u = (u & 0x80000000u) ? (u ^ 0x80000000u) : ~u;
    return __uint_as_float(u);
}

// ---- kernel 1: h[e] = 0.5*||e||^2, init keys / count / loss --------------
__global__ void vq_prep(const float* __restrict__ emb, float* __restrict__ h,
                        unsigned long long* __restrict__ k1,
                        unsigned long long* __restrict__ k2,
                        int* __restrict__ cnt, float* __restrict__ out) {
    int t = blockIdx.x * 256 + threadIdx.x;   // grid 64*256 = 16384
    if (t < NE_) {
        const float4* er = (const float4*)(emb + (size_t)t * 64);
        float4 a = {0.f, 0.f, 0.f, 0.f};
#pragma unroll
        for (int k = 0; k < 16; k++) {
            float4 e4 = er[k];
            a.x = fmaf(e4.x, e4.x, a.x);
            a.y = fmaf(e4.y, e4.y, a.y);
            a.z = fmaf(e4.z, e4.z, a.z);
            a.w = fmaf(e4.w, e4.w, a.w);
        }
        h[t] = 0.5f * ((a.x + a.y) + (a.z + a.w));
    }
    k1[t] = ~0ULL;
    k2[t] = ~0ULL;
    if (t == 0) { *cnt = 0; out[LOSS_OFF] = 0.f; }
}

// ---- kernel 2: main scan. 32 row-groups x 8 e-chunks. ---------------------
// Each thread = one z-row (64 f32 in regs). Embeddings staged into LDS.
__global__ __launch_bounds__(512) void vq_scan(
        const float* __restrict__ z, const float* __restrict__ emb,
        const float* __restrict__ h,
        unsigned long long* __restrict__ k1,
        unsigned long long* __restrict__ k2) {
    __shared__ float4 se[256 * 16];   // 64 KB: 256 embeddings x 64 f32
    __shared__ float  sh[256];        // their 0.5*||e||^2

    const int tid = threadIdx.x;
    const int rg = blockIdx.x >> 3;   // row group 0..31
    const int ec = blockIdx.x & 7;    // embedding chunk 0..7
    const int row = rg * 512 + tid;
    const int b = row >> 10, hw = row & 1023;
    const float* zp = z + (size_t)b * CHW_ + hw;

    float4 zv[16];
#pragma unroll
    for (int k = 0; k < 16; k++) {
        zv[k].x = zp[(4 * k + 0) * HW_];
        zv[k].y = zp[(4 * k + 1) * HW_];
        zv[k].z = zp[(4 * k + 2) * HW_];
        zv[k].w = zp[(4 * k + 3) * HW_];
    }

    float s1 = INFINITY, s2 = INFINITY;
    int i1 = 0, i2 = 0;
    const int e0 = ec * 512;

    for (int half = 0; half < 2; half++) {
        int base = e0 + half * 256;
        __syncthreads();
        const float4* src = (const float4*)(emb + (size_t)base * 64);
        for (int i = tid; i < 4096; i += 512) se[i] = src[i];
        if (tid < 256) sh[tid] = h[base + tid];
        __syncthreads();

        for (int el = 0; el < 256; el++) {
            const float4* ev = &se[el * 16];
            float4 a = {0.f, 0.f, 0.f, 0.f};
#pragma unroll
            for (int k = 0; k < 16; k++) {
                float4 e4 = ev[k];
                a.x = fmaf(e4.x, zv[k].x, a.x);
                a.y = fmaf(e4.y, zv[k].y, a.y);
                a.z = fmaf(e4.z, zv[k].z, a.z);
                a.w = fmaf(e4.w, zv[k].w, a.w);
            }
            float dot = (a.x + a.y) + (a.z + a.w);
            float score = sh[el] - dot;   // 0.5||e||^2 - z.e  (monotone in d2)
            int e = base + el;
            if (score < s1)      { s2 = s1; i2 = i1; s1 = score; i1 = e; }
            else if (score < s2) { s2 = score; i2 = e; }
        }
    }

    // merge this chunk's top-2 into the row's global top-2
    unsigned long long c = packKey(s1, i1);
    unsigned long long old = atomicMin(&k1[row], c);
    unsigned long long disp = (old > c) ? old : c;   // loser of the k1 duel
    if (disp != ~0ULL) atomicMin(&k2[row], disp);
    atomicMin(&k2[row], packKey(s2, i2));
}

// ---- kernel 3: confident rows -> outputs; near-ties -> refine list -------
__global__ void vq_final(const float* __restrict__ z, const float* __restrict__ emb,
                         const unsigned long long* __restrict__ k1,
                         const unsigned long long* __restrict__ k2,
                         int* __restrict__ cnt, int* __restrict__ rows,
                         float* __restrict__ out) {
    int n = blockIdx.x * 256 + threadIdx.x;   // 64 blocks
    unsigned long long key1 = k1[n];
    float s1 = keyScore(key1);
    float s2 = keyScore(k2[n]);
    int idx = (int)(unsigned)(key1 & 0xffffffffULL);
    float lsum = 0.f;

    if ((s2 - s1) < EPS_GAP) {
        int slot = atomicAdd(cnt, 1);
        rows[slot] = n;                        // fp64 pass will handle this row
    } else {
        int b = n >> 10, hw = n & 1023;
        const float* er = emb + (size_t)idx * 64;
        float* zq = out + (size_t)b * CHW_ + hw;
        const float* zp = z + (size_t)b * CHW_ + hw;
#pragma unroll
        for (int c = 0; c < 64; c++) {
            float e = er[c];
            float d = e - zp[c * HW_];
            zq[c * HW_] = e;
            lsum = fmaf(d, d, lsum);
        }
        out[IDX_OFF + n] = (float)idx;
    }

    // wave-level loss reduction, one atomic per wave
#pragma unroll
    for (int off = 32; off; off >>= 1) lsum += __shfl_down(lsum, off);
    if ((threadIdx.x & 63) == 0) atomicAdd(&out[LOSS_OFF], lsum * LOSS_SCALE);
}

// ---- kernel 4: fp64 rescan of ambiguous rows (expected count ~ tens) -----
__global__ __launch_bounds__(256) void vq_refine(
        const float* __restrict__ z, const float* __restrict__ emb,
        const int* __restrict__ cnt, const int* __restrict__ rows,
        float* __restrict__ out) {
    __shared__ double zs[64];
    __shared__ double rs[256];
    __shared__ int    ri[256];
    const int tid = threadIdx.x;
    const int count = *cnt;

    for (int i = blockIdx.x; i < count; i += gridDim.x) {
        int n = rows[i];
        int b = n >> 10, hw = n & 1023;
        if (tid < 64) zs[tid] = (double)z[(size_t)b * CHW_ + tid * HW_ + hw];
        __syncthreads();

        double best = 1e300;
        int besti = 0;
        for (int e = tid * 16; e < tid * 16 + 16; e++) {
            const float* er = emb + (size_t)e * 64;
            double dot = 0.0, nrm = 0.0;
            for (int k = 0; k < 64; k++) {
                double ev = (double)er[k];
                dot = fma(ev, zs[k], dot);
                nrm = fma(ev, ev, nrm);
            }
            double score = 0.5 * nrm - dot;
            if (score < best) { best = score; besti = e; }
        }
        rs[tid] = best; ri[tid] = besti;
        __syncthreads();
        for (int s = 128; s; s >>= 1) {
            if (tid < s) {
                if (rs[tid + s] < rs[tid] ||
                    (rs[tid + s] == rs[tid] && ri[tid + s] < ri[tid])) {
                    rs[tid] = rs[tid + s];
                    ri[tid] = ri[tid + s];
                }
            }
            __syncthreads();
        }
        int idx = ri[0];
        if (tid < 64) {
            float e = emb[(size_t)idx * 64 + tid];
            float zz = (float)zs[tid];
            float d = e - zz;
            out[(size_t)b * CHW_ + tid * HW_ + hw] = e;
            float l = d * d;
#pragma unroll
            for (int off = 32; off; off >>= 1) l += __shfl_down(l, off);
            if (tid == 0) {
                atomicAdd(&out[LOSS_OFF], l * LOSS_SCALE);
                out[IDX_OFF + n] = (float)idx;
            }
        }
        __syncthreads();   // protect zs before next row
    }
}

extern "C" void kernel_launch(void* const* d_in, const int* in_sizes, int n_in,
                              void* d_out, int out_size, void* d_ws, size_t ws_size,
                              hipStream_t stream) {
    const float* z   = (const float*)d_in[0];
    const float* emb = (const float*)d_in[1];
    float* out = (float*)d_out;
    char* ws = (char*)d_ws;

    float* h                 = (float*)ws;                          // 16 KB
    unsigned long long* k1   = (unsigned long long*)(ws + 16384);   // 128 KB
    unsigned long long* k2   = (unsigned long long*)(ws + 16384 + 131072); // 128 KB
    int* cnt                 = (int*)(ws + 16384 + 262144);         // 4 B (+pad)
    int* rows                = (int*)(ws + 16384 + 262144 + 64);    // 64 KB

    vq_prep  <<<64, 256, 0, stream>>>(emb, h, k1, k2, cnt, out);
    vq_scan  <<<256, 512, 0, stream>>>(z, emb, h, k1, k2);
    vq_final <<<64, 256, 0, stream>>>(z, emb, k1, k2, cnt, rows, out);
    vq_refine<<<64, 256, 0, stream>>>(z, emb, cnt, rows, out);
}

// Round 2
// 340.336 us; speedup vs baseline: 1.9428x; 1.9428x over previous
//
#include <hip/hip_runtime.h>

#define C_ 64
#define HW_ 1024
#define NE_ 4096
#define CHW_ 65536          // C_*HW_
#define ZQ_SIZE 1048576
#define LOSS_OFF ZQ_SIZE
#define IDX_OFF (ZQ_SIZE + 1)
#define EPS_GAP 2e-3f
#define LOSS_SCALE (1.25f / 1048576.f)

// monotonic float<->u64 key (score hi32, idx lo32): atomicMin == argmin w/ low-idx tie-break
__device__ __forceinline__ unsigned long long packKey(float s, int idx) {
    unsigned u = __float_as_uint(s);
    u = (u & 0x80000000u) ? ~u : (u | 0x80000000u);
    return ((unsigned long long)u << 32) | (unsigned)idx;
}
__device__ __forceinline__ float keyScore(unsigned long long k) {
    unsigned u = (unsigned)(k >> 32);
    u = (u & 0x80000000u) ? (u ^ 0x80000000u) : ~u;
    return __uint_as_float(u);
}

__device__ __forceinline__ void mergeTop2(unsigned long long* k1,
                                          unsigned long long* k2, int row,
                                          float s1, int i1, float s2, int i2) {
    unsigned long long c = packKey(s1, i1);
    unsigned long long old = atomicMin(&k1[row], c);
    unsigned long long disp = (old > c) ? old : c;     // loser of the k1 duel
    if (disp != ~0ULL) atomicMin(&k2[row], disp);
    atomicMin(&k2[row], packKey(s2, i2));
}

// ---- kernel 1: h[e]=0.5||e||^2, init keys, zero loss ---------------------
__global__ void vq_prep(const float* __restrict__ emb, float* __restrict__ h,
                        unsigned long long* __restrict__ k1,
                        unsigned long long* __restrict__ k2,
                        float* __restrict__ out) {
    int t = blockIdx.x * 256 + threadIdx.x;   // 64*256 = 16384
    if (t < NE_) {
        const float4* er = (const float4*)(emb + (size_t)t * 64);
        float4 a = {0.f, 0.f, 0.f, 0.f};
#pragma unroll
        for (int k = 0; k < 16; k++) {
            float4 e4 = er[k];
            a.x = fmaf(e4.x, e4.x, a.x);
            a.y = fmaf(e4.y, e4.y, a.y);
            a.z = fmaf(e4.z, e4.z, a.z);
            a.w = fmaf(e4.w, e4.w, a.w);
        }
        h[t] = 0.5f * ((a.x + a.y) + (a.z + a.w));
    }
    k1[t] = ~0ULL;
    k2[t] = ~0ULL;
    if (t == 0) out[LOSS_OFF] = 0.f;
}

// ---- kernel 2: main scan. 16 row-groups x 16 e-chunks; 2 rows/thread -----
__global__ __launch_bounds__(512) void vq_scan(
        const float* __restrict__ z, const float* __restrict__ emb,
        const float* __restrict__ h,
        unsigned long long* __restrict__ k1,
        unsigned long long* __restrict__ k2) {
    __shared__ float4 se[256 * 16];   // 64 KB: 256 embeddings x 64 f32
    __shared__ float  sh[256];

    const int tid = threadIdx.x;
    const int rg = blockIdx.x >> 4;   // 0..15 (= batch index; 1024 rows each)
    const int ec = blockIdx.x & 15;   // 0..15 (256 embeddings each)
    const int row0 = rg * 1024 + tid;       // hw = tid
    const int row1 = row0 + 512;            // hw = tid + 512
    const float* zp = z + (size_t)rg * CHW_ + tid;

    float4 z0[16], z1[16];
#pragma unroll
    for (int k = 0; k < 16; k++) {
        z0[k].x = zp[(4 * k + 0) * HW_];
        z0[k].y = zp[(4 * k + 1) * HW_];
        z0[k].z = zp[(4 * k + 2) * HW_];
        z0[k].w = zp[(4 * k + 3) * HW_];
        z1[k].x = zp[512 + (4 * k + 0) * HW_];
        z1[k].y = zp[512 + (4 * k + 1) * HW_];
        z1[k].z = zp[512 + (4 * k + 2) * HW_];
        z1[k].w = zp[512 + (4 * k + 3) * HW_];
    }

    const int base = ec * 256;
    const float4* src = (const float4*)(emb + (size_t)base * 64);
    for (int i = tid; i < 4096; i += 512) se[i] = src[i];
    if (tid < 256) sh[tid] = h[base + tid];
    __syncthreads();

    float s1a = INFINITY, s2a = INFINITY, s1b = INFINITY, s2b = INFINITY;
    int i1a = 0, i2a = 0, i1b = 0, i2b = 0;

    for (int el = 0; el < 256; el++) {
        const float4* ev = &se[el * 16];
        float4 a0 = {0.f, 0.f, 0.f, 0.f};
        float4 a1 = {0.f, 0.f, 0.f, 0.f};
#pragma unroll
        for (int k = 0; k < 16; k++) {
            float4 e4 = ev[k];
            a0.x = fmaf(e4.x, z0[k].x, a0.x);
            a0.y = fmaf(e4.y, z0[k].y, a0.y);
            a0.z = fmaf(e4.z, z0[k].z, a0.z);
            a0.w = fmaf(e4.w, z0[k].w, a0.w);
            a1.x = fmaf(e4.x, z1[k].x, a1.x);
            a1.y = fmaf(e4.y, z1[k].y, a1.y);
            a1.z = fmaf(e4.z, z1[k].z, a1.z);
            a1.w = fmaf(e4.w, z1[k].w, a1.w);
        }
        float d0 = (a0.x + a0.y) + (a0.z + a0.w);
        float d1 = (a1.x + a1.y) + (a1.z + a1.w);
        float sc0 = sh[el] - d0;
        float sc1 = sh[el] - d1;
        int e = base + el;
        if (sc0 < s1a)      { s2a = s1a; i2a = i1a; s1a = sc0; i1a = e; }
        else if (sc0 < s2a) { s2a = sc0; i2a = e; }
        if (sc1 < s1b)      { s2b = s1b; i2b = i1b; s1b = sc1; i1b = e; }
        else if (sc1 < s2b) { s2b = sc1; i2b = e; }
    }

    mergeTop2(k1, k2, row0, s1a, i1a, s2a, i2a);
    mergeTop2(k1, k2, row1, s1b, i1b, s2b, i2b);
}

// ---- kernel 3: outputs; inline wave-cooperative fp64 rescan for near-ties
__global__ __launch_bounds__(256) void vq_final(
        const float* __restrict__ z, const float* __restrict__ emb,
        const unsigned long long* __restrict__ k1v,
        const unsigned long long* __restrict__ k2v,
        float* __restrict__ out) {
    int n = blockIdx.x * 256 + threadIdx.x;   // 64 blocks
    unsigned long long key1 = k1v[n];
    float s1 = keyScore(key1);
    float s2 = keyScore(k2v[n]);
    int idx = (int)(unsigned)(key1 & 0xffffffffULL);

    bool ambig = (s2 - s1) < EPS_GAP;          // NaN-safe: false
    if (__any(ambig)) {                        // rare path; zero cost when empty
        unsigned long long m = __ballot(ambig);
        const int lane = threadIdx.x & 63;
        const int wbase = blockIdx.x * 256 + (threadIdx.x & ~63);
        while (m) {
            int src = __ffsll((long long)m) - 1;
            m &= m - 1;
            int rn = wbase + src;
            int b = rn >> 10, hw = rn & 1023;
            const float* zrow = z + (size_t)b * CHW_ + hw;
            double best = 1e300;
            int bi = 0;
            for (int e = lane; e < NE_; e += 64) {
                const float* er = emb + (size_t)e * 64;
                double dot = 0.0, nrm = 0.0;
                for (int k = 0; k < 64; k++) {
                    double ev = (double)er[k];
                    dot = fma(ev, (double)zrow[k * HW_], dot);
                    nrm = fma(ev, ev, nrm);
                }
                double sc = 0.5 * nrm - dot;
                if (sc < best) { best = sc; bi = e; }
            }
            for (int off = 32; off; off >>= 1) {
                double ob = __shfl_xor(best, off);
                int oi = __shfl_xor(bi, off);
                if (ob < best || (ob == best && oi < bi)) { best = ob; bi = oi; }
            }
            if (lane == src) idx = bi;
        }
    }

    int b = n >> 10, hw = n & 1023;
    const float* er = emb + (size_t)idx * 64;
    float* zq = out + (size_t)b * CHW_ + hw;
    const float* zp = z + (size_t)b * CHW_ + hw;
    float lsum = 0.f;
#pragma unroll
    for (int c = 0; c < 64; c++) {
        float e = er[c];
        float d = e - zp[c * HW_];
        zq[c * HW_] = e;
        lsum = fmaf(d, d, lsum);
    }
    out[IDX_OFF + n] = (float)idx;

#pragma unroll
    for (int off = 32; off; off >>= 1) lsum += __shfl_down(lsum, off);
    if ((threadIdx.x & 63) == 0) atomicAdd(&out[LOSS_OFF], lsum * LOSS_SCALE);
}

extern "C" void kernel_launch(void* const* d_in, const int* in_sizes, int n_in,
                              void* d_out, int out_size, void* d_ws, size_t ws_size,
                              hipStream_t stream) {
    const float* z   = (const float*)d_in[0];
    const float* emb = (const float*)d_in[1];
    float* out = (float*)d_out;
    char* ws = (char*)d_ws;

    float* h               = (float*)ws;                          // 16 KB
    unsigned long long* k1 = (unsigned long long*)(ws + 16384);   // 128 KB
    unsigned long long* k2 = (unsigned long long*)(ws + 16384 + 131072); // 128 KB

    vq_prep <<<64, 256, 0, stream>>>(emb, h, k1, k2, out);
    vq_scan <<<256, 512, 0, stream>>>(z, emb, h, k1, k2);
    vq_final<<<64, 256, 0, stream>>>(z, emb, k1, k2, out);
}